// Round 6
// baseline (313.524 us; speedup 1.0000x reference)
//
#include <hip/hip_runtime.h>
#include <math.h>

// Fused Conv3d(3->16, k=3, valid) + bias + min over D + softmax over C.
// N=16, CIN=3, COUT=16, K=3, D=H=W=64 -> out [16,16,62,62] fp32.
//
// R6: three kernels.
//  1) init_enc: fill d_out with encoded +inf (d_out is poisoned each call).
//  2) conv_min: R5 mapping (co=tid&15, 2x4 px/thread, tile 8x16) with
//     - d-range split in two per (n,tile): grid 1024 = 4 blocks/CU
//       (at 8 px/thread one kernel over full d is capped at 2 waves/SIMD
//       device-wide; R3/R5 stuck at 11% occupancy / VALUBusy ~61%).
//     - CH=2 chunks, ACC ring 4 slots (32 VGPR vs R5's 48).
//     - async DOUBLE-BUFFERED staging via global_load_lds width=16:
//       no global->VGPR->LDS roundtrip (R5 held ~60+ VGPRs of pipelined
//       loads), and chunk c+1 stays in flight across compute of chunk c.
//     - halves combine with order-preserving uint atomicMin into d_out.
//  3) finalize_softmax: decode, +bias, softmax over 16 co, write in place.
// NO launch_bounds floor anywhere (R2/R4: caps below ~160 VGPR -> spill).

#define CH 2
#define NSLOT 300                 // 3ci * CH * 10 rows * 5 f4-groups
#define NINST 5                   // ceil(300/64) wave-instructions
#define BUFFLT (NINST * 64 * 4)   // 1280 floats per buffer (pad to 320 f4)

#define SX(b, ci, dd, r, c) sxbuf[b][((((ci) * CH + (dd)) * 10 + (r)) * 20) + (c)]

// taps (o,kh): 3 kw x 4 p x 3 kd FMAs; kd->slot: 0->dd+2, 1->dd+1, 2->dd
#define TAPS(o, kh)                                                        \
    _Pragma("unroll")                                                      \
    for (int kw = 0; kw < 3; ++kw) {                                       \
        const float wk0 = wreg[0  + (kh) * 3 + kw];                        \
        const float wk1 = wreg[9  + (kh) * 3 + kw];                        \
        const float wk2 = wreg[18 + (kh) * 3 + kw];                        \
        _Pragma("unroll")                                                  \
        for (int p = 0; p < 4; ++p) {                                      \
            const float xv = row[kw + p];                                  \
            ACC[dd + 2][o][p] = fmaf(xv, wk0, ACC[dd + 2][o][p]);          \
            ACC[dd + 1][o][p] = fmaf(xv, wk1, ACC[dd + 1][o][p]);          \
            ACC[dd + 0][o][p] = fmaf(xv, wk2, ACC[dd + 0][o][p]);          \
        }                                                                  \
    }

// order-preserving float<->uint map (ascending): min(float) == min(uint)
__device__ __forceinline__ unsigned enc_f32(float f) {
    unsigned b = __float_as_uint(f);
    return (b & 0x80000000u) ? ~b : (b | 0x80000000u);
}
__device__ __forceinline__ float dec_f32(unsigned u) {
    return __uint_as_float((u & 0x80000000u) ? (u ^ 0x80000000u) : ~u);
}

__global__ __launch_bounds__(256) void init_enc(unsigned* __restrict__ o, int n4) {
    int i = blockIdx.x * 256 + threadIdx.x;
    if (i < n4) ((uint4*)o)[i] = make_uint4(~0u, ~0u, ~0u, ~0u);
}

__global__ __launch_bounds__(256) void conv_min(
    const float* __restrict__ x,     // [16,3,64,64,64]
    const float* __restrict__ wgt,   // [16,3,3,3,3]
    unsigned* __restrict__ outw)     // [16,16,62,62] encoded mins
{
    const int tid  = threadIdx.x;
    const int lane = tid & 63;
    const int wave = tid >> 6;
    const int co   = tid & 15;         // output channel on lane bits 0..3
    const int s    = tid >> 4;         // strip id
    const int hh   = (s >> 2) * 2;     // output rows hh, hh+1
    const int ww   = (s & 3) * 4;      // output cols ww..ww+3
    const int n    = blockIdx.z >> 1;
    const int half = blockIdx.z & 1;
    const int h0   = blockIdx.y * 8;
    const int w0   = blockIdx.x * 16;

    // half 0: d 0..31  -> d' valid [0,29]; half 1: d 28..63 -> d' [30,61]
    const int dstart = half ? 28 : 0;
    const int nchunk = half ? 18 : 16;
    const int dlo    = half ? 30 : 0;
    const int dhi    = half ? 61 : 29;

    // double-buffered staged x; layout linear in (rowid,g) so the
    // global_load_lds wave-uniform-base + lane*16 rule is met exactly.
    __shared__ __align__(16) float sxbuf[2][BUFFLT];
    // weights [co][ci][28]: 16B-aligned rows, worst 2-way bank alias (free)
    __shared__ __align__(16) float wlds[16][3][28];

    for (int i = tid; i < 16 * 81; i += 256) {
        int c2 = i / 81, j = i - c2 * 81;
        int ci = j / 27, t = j - ci * 27;
        wlds[c2][ci][t] = wgt[i];
    }

    float ACC[CH + 2][2][4], mv[2][4];
#pragma unroll
    for (int sl = 0; sl < CH + 2; ++sl)
#pragma unroll
        for (int o = 0; o < 2; ++o)
#pragma unroll
            for (int p = 0; p < 4; ++p) ACC[sl][o][p] = 0.f;
#pragma unroll
    for (int o = 0; o < 2; ++o)
#pragma unroll
        for (int p = 0; p < 4; ++p) mv[o][p] = 1e30f;

    const float* xn = x + (size_t)n * 3 * 64 * 64 * 64;

    // async-stage chunk c into buffer b (per-wave share of NINST insts)
    auto issue = [&](int c, int b) {
        const int d0 = dstart + c * CH;
        for (int t = wave; t < NINST; t += 4) {
            int s4 = t * 64 + lane;
            int s2 = s4 < NSLOT ? s4 : NSLOT - 1;  // pad lanes: dup last
            int rowid = s2 / 5;                    // (ci*CH+dd)*10 + r
            int g     = s2 - rowid * 5;
            int ci    = rowid / (CH * 10);
            int rem   = rowid - ci * (CH * 10);
            int dd    = rem / 10;
            int r     = rem - dd * 10;
            int gh    = min(h0 + r, 63);           // edge halo, unused
            int gw    = min(w0 + g * 4, 60);       // cols >=62 unused
            const float* gp =
                &xn[(((size_t)ci * 64 + (d0 + dd)) * 64 + gh) * 64 + gw];
            float* lp = &sxbuf[b][t * 256];        // wave-uniform base
            __builtin_amdgcn_global_load_lds(
                (const __attribute__((address_space(1))) unsigned*)gp,
                (__attribute__((address_space(3))) unsigned*)lp, 16, 0, 0);
        }
    };

    issue(0, 0);
    for (int c = 0; c < nchunk; ++c) {
        __syncthreads();                 // drains loads(c); compute(c-1) done
        if (c + 1 < nchunk) issue(c + 1, (c + 1) & 1);  // in flight over compute(c)
        const int b  = c & 1;
        const int d0 = dstart + c * CH;

#pragma unroll
        for (int ci = 0; ci < 3; ++ci) {
            float wreg[27];
#pragma unroll
            for (int q = 0; q < 27; ++q) wreg[q] = wlds[co][ci][q];
#pragma unroll
            for (int dd = 0; dd < CH; ++dd) {
#pragma unroll
                for (int r = 0; r < 4; ++r) {
                    const float4 a  = *(const float4*)&SX(b, ci, dd, hh + r, ww);
                    const float2 b2 = *(const float2*)&SX(b, ci, dd, hh + r, ww + 4);
                    const float row[6] = {a.x, a.y, a.z, a.w, b2.x, b2.y};
                    if (r == 0) { TAPS(0, 0) }
                    if (r == 1) { TAPS(0, 1) TAPS(1, 0) }
                    if (r == 2) { TAPS(0, 2) TAPS(1, 1) }
                    if (r == 3) { TAPS(1, 2) }
                }
            }
        }

        // slots 0..CH-1 now complete (d' = d0-2+sl); min if in this half
#pragma unroll
        for (int sl = 0; sl < CH; ++sl) {
            const int dp = d0 - 2 + sl;
            if (dp >= dlo && dp <= dhi) {
#pragma unroll
                for (int o = 0; o < 2; ++o)
#pragma unroll
                    for (int p = 0; p < 4; ++p)
                        mv[o][p] = fminf(mv[o][p], ACC[sl][o][p]);
            }
        }
#pragma unroll
        for (int o = 0; o < 2; ++o)
#pragma unroll
            for (int p = 0; p < 4; ++p) {
                ACC[0][o][p] = ACC[CH][o][p];
                ACC[1][o][p] = ACC[CH + 1][o][p];
                ACC[CH][o][p] = 0.f;
                ACC[CH + 1][o][p] = 0.f;
            }
    }

    // combine halves: order-preserving encoded atomicMin into d_out
#pragma unroll
    for (int o = 0; o < 2; ++o) {
        const int hp = h0 + hh + o;
#pragma unroll
        for (int p = 0; p < 4; ++p) {
            const int wp = w0 + ww + p;
            if (hp < 62 && wp < 62)
                atomicMin(&outw[(((size_t)n * 16 + co) * 62 + hp) * 62 + wp],
                          enc_f32(mv[o][p]));
        }
    }
}

__global__ __launch_bounds__(256) void finalize_softmax(
    unsigned* __restrict__ io,       // encoded mins in, float softmax out
    const float* __restrict__ bias)  // [16]
{
    const int PX = 62 * 62;
    const int id = blockIdx.x * 256 + threadIdx.x;
    if (id >= 16 * PX) return;
    const int n  = id / PX;
    const int hw = id - n * PX;

    float v[16], mx = -1e30f;
#pragma unroll
    for (int c = 0; c < 16; ++c) {
        v[c] = dec_f32(io[((size_t)n * 16 + c) * PX + hw]) + bias[c];
        mx = fmaxf(mx, v[c]);
    }
    float sum = 0.f;
#pragma unroll
    for (int c = 0; c < 16; ++c) { v[c] = __expf(v[c] - mx); sum += v[c]; }
    const float inv = 1.f / sum;
#pragma unroll
    for (int c = 0; c < 16; ++c)
        io[((size_t)n * 16 + c) * PX + hw] = __float_as_uint(v[c] * inv);
}

extern "C" void kernel_launch(void* const* d_in, const int* in_sizes, int n_in,
                              void* d_out, int out_size, void* d_ws, size_t ws_size,
                              hipStream_t stream) {
    const float* x    = (const float*)d_in[0];
    const float* wgt  = (const float*)d_in[1];
    const float* bias = (const float*)d_in[2];
    unsigned* outw    = (unsigned*)d_out;

    const int n4 = (16 * 16 * 62 * 62) / 4;           // 246016 uint4
    hipLaunchKernelGGL(init_enc, dim3(n4 / 256), dim3(256), 0, stream,
                       outw, n4);
    hipLaunchKernelGGL(conv_min, dim3(4, 8, 32), dim3(256), 0, stream,
                       x, wgt, outw);
    const int npix = 16 * 62 * 62;                    // 61504
    hipLaunchKernelGGL(finalize_softmax, dim3((npix + 255) / 256), dim3(256),
                       0, stream, outw, bias);
}